// Round 1
// baseline (3481.925 us; speedup 1.0000x reference)
//
#include <hip/hip_runtime.h>
#include <hip/hip_bf16.h>

// Problem constants
#define Bn   8
#define Ln   1024
#define DMn  1024
#define DSn  512
#define Hn   16
#define HDn  1024   // H*DK == H*DV
#define KCn  1536   // DM + DS

// ws layout (float offsets)
#define OFF_QH   ((size_t)0)            // 8192x1024, later reused as preLN
#define OFF_KH   ((size_t)8388608)
#define OFF_VH   ((size_t)16777216)
#define OFF_PV   ((size_t)25165824)
#define OFF_SPQ  ((size_t)33554432)     // 8x1024 each below
#define OFF_SPK  (OFF_SPQ + 8192)
#define OFF_SPV  (OFF_SPK + 8192)
#define OFF_SQ   (OFF_SPV + 8192)
#define OFF_FCS  (OFF_SQ  + 8192)
#define OFF_SOUT (OFF_FCS + 8192)
#define OFF_SUP  (OFF_SOUT + 8192)      // 8x512
#define OFF_FLAG (OFF_SUP + 4096)
#define WS_FLOATS (OFF_FLAG + 16)

// d_out layout (float offsets): out (8M) | su (4096) | attn (128M)
#define OUT_SU   ((size_t)8388608)
#define OUT_ATT  ((size_t)8392704)

// ---------------- mask dtype detection (bool delivery format is ambiguous) ----
__global__ void detect_mask_kernel(const unsigned int* __restrict__ mw, int* __restrict__ flag) {
    __shared__ int allInt, allFloat;
    if (threadIdx.x == 0) { allInt = 1; allFloat = 1; }
    __syncthreads();
    int aI = 1, aF = 1;
    for (int i = 0; i < 16; i++) {
        unsigned int w = mw[threadIdx.x + 256 * i];
        if (w > 1u) aI = 0;
        if (!(w == 0u || w == 0x3f800000u)) aF = 0;
    }
    if (!aI) atomicAnd(&allInt, 0);
    if (!aF) atomicAnd(&allFloat, 0);
    __syncthreads();
    if (threadIdx.x == 0) *flag = allInt ? 0 : (allFloat ? 2 : 1);  // 0=int32 1=byte 2=f32
}

// ---------------- per-batch state-projection parts (bias folded in) ----------
__global__ __launch_bounds__(256) void state_proj_kernel(
    const float* __restrict__ state,
    const float* __restrict__ Wq, const float* __restrict__ bq,
    const float* __restrict__ Wk, const float* __restrict__ bk,
    const float* __restrict__ Wv, const float* __restrict__ bv,
    const float* __restrict__ Wsq, const float* __restrict__ bsq,
    const float* __restrict__ Wfc, const float* __restrict__ bfc,
    float* __restrict__ ws)
{
    const int widx = blockIdx.x, b = blockIdx.y, g = blockIdx.z;
    const float* W; const float* bias; float* out; int koff, ldw;
    switch (widx) {
        case 0:  W = Wq;  bias = bq;  out = ws + OFF_SPQ; koff = DMn; ldw = KCn; break;
        case 1:  W = Wk;  bias = bk;  out = ws + OFF_SPK; koff = DMn; ldw = KCn; break;
        case 2:  W = Wv;  bias = bv;  out = ws + OFF_SPV; koff = DMn; ldw = KCn; break;
        case 3:  W = Wsq; bias = bsq; out = ws + OFF_SQ;  koff = 0;   ldw = DSn; break;
        default: W = Wfc; bias = bfc; out = ws + OFF_FCS; koff = DMn; ldw = KCn; break;
    }
    const int wv = threadIdx.x >> 6, lane = threadIdx.x & 63;
    const float* st = state + (size_t)b * DSn;
    for (int o = 0; o < 16; o++) {
        int n = g * 64 + wv * 16 + o;
        float s = 0.f;
        for (int j = lane; j < DSn; j += 64) s = fmaf(st[j], W[(size_t)n * ldw + koff + j], s);
        for (int off = 32; off; off >>= 1) s += __shfl_xor(s, off);
        if (lane == 0) out[(size_t)b * 1024 + n] = s + bias[n];
    }
}

// ---------------- C = A * W^T + rowadd[batch] (+resid) ; A:(M,K) W:(N,ldw) ---
__global__ __launch_bounds__(256) void gemm_nt_kernel(
    const float* __restrict__ A, const float* __restrict__ W,
    const float* __restrict__ rowadd, const float* __restrict__ resid,
    float* __restrict__ C, int M, int N, int K, int ldw)
{
    __shared__ float As[16][132];
    __shared__ float Bs[16][132];
    const int t = threadIdx.x;
    const int m0 = blockIdx.y * 128, n0 = blockIdx.x * 128;
    const int tx = t & 15, ty = t >> 4;
    float acc[8][8];
#pragma unroll
    for (int i = 0; i < 8; i++)
#pragma unroll
        for (int j = 0; j < 8; j++) acc[i][j] = 0.f;

    for (int k0 = 0; k0 < K; k0 += 16) {
        float4 av[2], bv[2];
#pragma unroll
        for (int i = 0; i < 2; i++) {
            int idx = i * 256 + t;
            int r = idx >> 2, c4 = (idx & 3) << 2;
            av[i] = *(const float4*)(A + (size_t)(m0 + r) * K + k0 + c4);
            bv[i] = *(const float4*)(W + (size_t)(n0 + r) * ldw + k0 + c4);
        }
        __syncthreads();
#pragma unroll
        for (int i = 0; i < 2; i++) {
            int idx = i * 256 + t;
            int r = idx >> 2, c4 = (idx & 3) << 2;
            As[c4 + 0][r] = av[i].x; As[c4 + 1][r] = av[i].y; As[c4 + 2][r] = av[i].z; As[c4 + 3][r] = av[i].w;
            Bs[c4 + 0][r] = bv[i].x; Bs[c4 + 1][r] = bv[i].y; Bs[c4 + 2][r] = bv[i].z; Bs[c4 + 3][r] = bv[i].w;
        }
        __syncthreads();
#pragma unroll
        for (int kk = 0; kk < 16; kk++) {
            float a[8], b[8];
            *(float4*)&a[0] = *(const float4*)&As[kk][ty * 8];
            *(float4*)&a[4] = *(const float4*)&As[kk][ty * 8 + 4];
            *(float4*)&b[0] = *(const float4*)&Bs[kk][tx * 8];
            *(float4*)&b[4] = *(const float4*)&Bs[kk][tx * 8 + 4];
#pragma unroll
            for (int i = 0; i < 8; i++)
#pragma unroll
                for (int j = 0; j < 8; j++) acc[i][j] = fmaf(a[i], b[j], acc[i][j]);
        }
    }
#pragma unroll
    for (int i = 0; i < 8; i++) {
        int m = m0 + ty * 8 + i;
        int bt = m >> 10;  // 1024 rows per batch
#pragma unroll
        for (int j = 0; j < 8; j += 4) {
            int n = n0 + tx * 8 + j;
            float4 o;
            o.x = acc[i][j + 0] + rowadd[(size_t)bt * N + n + 0];
            o.y = acc[i][j + 1] + rowadd[(size_t)bt * N + n + 1];
            o.z = acc[i][j + 2] + rowadd[(size_t)bt * N + n + 2];
            o.w = acc[i][j + 3] + rowadd[(size_t)bt * N + n + 3];
            if (resid) {
                float4 rv = *(const float4*)(resid + (size_t)m * N + n);
                o.x += rv.x; o.y += rv.y; o.z += rv.z; o.w += rv.w;
            }
            *(float4*)(C + (size_t)m * N + n) = o;
        }
    }
}

// ---------------- scores = qh*kh^T/8, masked, raw into d_out attn region -----
__global__ __launch_bounds__(256) void score_gemm_kernel(
    const float* __restrict__ qh, const float* __restrict__ kh,
    const void* __restrict__ mask, const int* __restrict__ flag,
    float* __restrict__ att)
{
    __shared__ float As[16][132];
    __shared__ float Bs[16][132];
    const int t = threadIdx.x;
    const int page = blockIdx.z;        // page = h*8 + b  (matches attn_flat layout)
    const int h = page >> 3, b = page & 7;
    const int m0 = blockIdx.y * 128, n0 = blockIdx.x * 128;
    const int tx = t & 15, ty = t >> 4;
    const float* Aq = qh + (size_t)b * Ln * HDn + h * 64;
    const float* Bk = kh + (size_t)b * Ln * HDn + h * 64;
    float acc[8][8];
#pragma unroll
    for (int i = 0; i < 8; i++)
#pragma unroll
        for (int j = 0; j < 8; j++) acc[i][j] = 0.f;

    for (int k0 = 0; k0 < 64; k0 += 16) {
        float4 av[2], bv[2];
#pragma unroll
        for (int i = 0; i < 2; i++) {
            int idx = i * 256 + t;
            int r = idx >> 2, c4 = (idx & 3) << 2;
            av[i] = *(const float4*)(Aq + (size_t)(m0 + r) * HDn + k0 + c4);
            bv[i] = *(const float4*)(Bk + (size_t)(n0 + r) * HDn + k0 + c4);
        }
        __syncthreads();
#pragma unroll
        for (int i = 0; i < 2; i++) {
            int idx = i * 256 + t;
            int r = idx >> 2, c4 = (idx & 3) << 2;
            As[c4 + 0][r] = av[i].x; As[c4 + 1][r] = av[i].y; As[c4 + 2][r] = av[i].z; As[c4 + 3][r] = av[i].w;
            Bs[c4 + 0][r] = bv[i].x; Bs[c4 + 1][r] = bv[i].y; Bs[c4 + 2][r] = bv[i].z; Bs[c4 + 3][r] = bv[i].w;
        }
        __syncthreads();
#pragma unroll
        for (int kk = 0; kk < 16; kk++) {
            float a[8], bb[8];
            *(float4*)&a[0] = *(const float4*)&As[kk][ty * 8];
            *(float4*)&a[4] = *(const float4*)&As[kk][ty * 8 + 4];
            *(float4*)&bb[0] = *(const float4*)&Bs[kk][tx * 8];
            *(float4*)&bb[4] = *(const float4*)&Bs[kk][tx * 8 + 4];
#pragma unroll
            for (int i = 0; i < 8; i++)
#pragma unroll
                for (int j = 0; j < 8; j++) acc[i][j] = fmaf(a[i], bb[j], acc[i][j]);
        }
    }
    const int fv = *flag;
    const unsigned char* m8 = (const unsigned char*)mask;
    const int* m32 = (const int*)mask;
    const float* mf = (const float*)mask;
    float* Cp = att + (size_t)page * Ln * Ln;
#pragma unroll
    for (int i = 0; i < 8; i++) {
        int m = m0 + ty * 8 + i;
        size_t mrow = ((size_t)b * Ln + m) * Ln;
        float vv[8];
#pragma unroll
        for (int j = 0; j < 8; j++) {
            int n = n0 + tx * 8 + j;
            bool mk = (fv == 0) ? (m32[mrow + n] != 0)
                     : (fv == 1) ? (m8[mrow + n] != 0)
                                 : (mf[mrow + n] != 0.0f);
            vv[j] = mk ? -1e9f : acc[i][j] * 0.125f;
        }
        *(float4*)(Cp + (size_t)m * Ln + n0 + tx * 8)     = make_float4(vv[0], vv[1], vv[2], vv[3]);
        *(float4*)(Cp + (size_t)m * Ln + n0 + tx * 8 + 4) = make_float4(vv[4], vv[5], vv[6], vv[7]);
    }
}

// ---------------- in-place row softmax over 1024 -----------------------------
__global__ __launch_bounds__(256) void softmax_kernel(float* __restrict__ att) {
    __shared__ float sm[4];
    const size_t row = blockIdx.x;
    float* p = att + row * 1024;
    const int t = threadIdx.x, lane = t & 63, wv = t >> 6;
    float4 v = *(float4*)(p + t * 4);
    float mx = fmaxf(fmaxf(v.x, v.y), fmaxf(v.z, v.w));
    for (int o = 32; o; o >>= 1) mx = fmaxf(mx, __shfl_xor(mx, o));
    if (lane == 0) sm[wv] = mx;
    __syncthreads();
    mx = fmaxf(fmaxf(sm[0], sm[1]), fmaxf(sm[2], sm[3]));
    __syncthreads();
    v.x = expf(v.x - mx); v.y = expf(v.y - mx); v.z = expf(v.z - mx); v.w = expf(v.w - mx);
    float s = v.x + v.y + v.z + v.w;
    for (int o = 32; o; o >>= 1) s += __shfl_xor(s, o);
    if (lane == 0) sm[wv] = s;
    __syncthreads();
    s = sm[0] + sm[1] + sm[2] + sm[3];
    float inv = 1.0f / s;
    v.x *= inv; v.y *= inv; v.z *= inv; v.w *= inv;
    *(float4*)(p + t * 4) = v;
}

// ---------------- pv = attn @ vh  (A:(1024,1024) B:(1024,64) per page) -------
__global__ __launch_bounds__(256) void pv_gemm_kernel(
    const float* __restrict__ att, const float* __restrict__ vh, float* __restrict__ pv)
{
    __shared__ float As[16][132];
    __shared__ float Bs[16][68];
    const int t = threadIdx.x;
    const int page = blockIdx.z;
    const int h = page >> 3, b = page & 7;
    const int m0 = blockIdx.y * 128;
    const int tx = t & 15, ty = t >> 4;
    const float* Ap = att + (size_t)page * Ln * Ln;
    const float* Bp = vh + (size_t)b * Ln * HDn + h * 64;
    float acc[8][4];
#pragma unroll
    for (int i = 0; i < 8; i++)
#pragma unroll
        for (int j = 0; j < 4; j++) acc[i][j] = 0.f;

    for (int k0 = 0; k0 < 1024; k0 += 16) {
        float4 av[2];
#pragma unroll
        for (int i = 0; i < 2; i++) {
            int idx = i * 256 + t;
            int r = idx >> 2, c4 = (idx & 3) << 2;
            av[i] = *(const float4*)(Ap + (size_t)(m0 + r) * Ln + k0 + c4);
        }
        const int kkl = t >> 4, c4b = (t & 15) << 2;
        float4 bv = *(const float4*)(Bp + (size_t)(k0 + kkl) * HDn + c4b);
        __syncthreads();
#pragma unroll
        for (int i = 0; i < 2; i++) {
            int idx = i * 256 + t;
            int r = idx >> 2, c4 = (idx & 3) << 2;
            As[c4 + 0][r] = av[i].x; As[c4 + 1][r] = av[i].y; As[c4 + 2][r] = av[i].z; As[c4 + 3][r] = av[i].w;
        }
        *(float4*)&Bs[kkl][c4b] = bv;
        __syncthreads();
#pragma unroll
        for (int kk = 0; kk < 16; kk++) {
            float a[8];
            float4 b4 = *(const float4*)&Bs[kk][tx * 4];
            *(float4*)&a[0] = *(const float4*)&As[kk][ty * 8];
            *(float4*)&a[4] = *(const float4*)&As[kk][ty * 8 + 4];
#pragma unroll
            for (int i = 0; i < 8; i++) {
                acc[i][0] = fmaf(a[i], b4.x, acc[i][0]);
                acc[i][1] = fmaf(a[i], b4.y, acc[i][1]);
                acc[i][2] = fmaf(a[i], b4.z, acc[i][2]);
                acc[i][3] = fmaf(a[i], b4.w, acc[i][3]);
            }
        }
    }
    float* Cp = pv + (size_t)b * Ln * HDn + h * 64;
#pragma unroll
    for (int i = 0; i < 8; i++) {
        int m = m0 + ty * 8 + i;
        *(float4*)(Cp + (size_t)m * HDn + tx * 4) =
            make_float4(acc[i][0], acc[i][1], acc[i][2], acc[i][3]);
    }
}

// ---------------- row LayerNorm over 1024 -> d_out ---------------------------
__global__ __launch_bounds__(256) void ln_kernel(
    const float* __restrict__ x, const float* __restrict__ g, const float* __restrict__ bb,
    float* __restrict__ out)
{
    __shared__ float sm[4];
    const size_t row = blockIdx.x;
    const int t = threadIdx.x, lane = t & 63, wv = t >> 6;
    float4 v = *(const float4*)(x + row * 1024 + t * 4);
    float s = v.x + v.y + v.z + v.w;
    for (int o = 32; o; o >>= 1) s += __shfl_xor(s, o);
    if (lane == 0) sm[wv] = s;
    __syncthreads();
    float mean = (sm[0] + sm[1] + sm[2] + sm[3]) * (1.0f / 1024.0f);
    __syncthreads();
    float dx = v.x - mean, dy = v.y - mean, dz = v.z - mean, dw = v.w - mean;
    float q = dx * dx + dy * dy + dz * dz + dw * dw;
    for (int o = 32; o; o >>= 1) q += __shfl_xor(q, o);
    if (lane == 0) sm[wv] = q;
    __syncthreads();
    float var = (sm[0] + sm[1] + sm[2] + sm[3]) * (1.0f / 1024.0f);
    float inv = 1.0f / sqrtf(var + 1e-5f);
    float4 gv = *(const float4*)(g + t * 4);
    float4 bv = *(const float4*)(bb + t * 4);
    float4 o4;
    o4.x = dx * inv * gv.x + bv.x;
    o4.y = dy * inv * gv.y + bv.y;
    o4.z = dz * inv * gv.z + bv.z;
    o4.w = dw * inv * gv.w + bv.w;
    *(float4*)(out + row * 1024 + t * 4) = o4;
}

// ---------------- state-query attention (no mask), s_out ---------------------
__global__ __launch_bounds__(256) void state_attn_kernel(
    const float* __restrict__ kh, const float* __restrict__ vh, const float* __restrict__ sq,
    float* __restrict__ s_out)
{
    __shared__ float sqs[64];
    __shared__ float pr[1024];
    __shared__ float red[4];
    __shared__ float part[4][64];
    const int h = blockIdx.x, b = blockIdx.y;
    const int t = threadIdx.x, lane = t & 63, wv = t >> 6;
    if (t < 64) sqs[t] = sq[(size_t)b * 1024 + h * 64 + t];
    __syncthreads();
    float sc[4];
    float mx = -1e30f;
#pragma unroll
    for (int i = 0; i < 4; i++) {
        int k = i * 256 + t;
        const float* kr = kh + ((size_t)b * Ln + k) * HDn + h * 64;
        float s = 0.f;
        for (int d = 0; d < 64; d++) s = fmaf(sqs[d], kr[d], s);
        sc[i] = s * 0.125f;
        mx = fmaxf(mx, sc[i]);
    }
    for (int o = 32; o; o >>= 1) mx = fmaxf(mx, __shfl_xor(mx, o));
    if (lane == 0) red[wv] = mx;
    __syncthreads();
    mx = fmaxf(fmaxf(red[0], red[1]), fmaxf(red[2], red[3]));
    __syncthreads();
    float sum = 0.f;
#pragma unroll
    for (int i = 0; i < 4; i++) { sc[i] = expf(sc[i] - mx); sum += sc[i]; }
    for (int o = 32; o; o >>= 1) sum += __shfl_xor(sum, o);
    if (lane == 0) red[wv] = sum;
    __syncthreads();
    sum = red[0] + red[1] + red[2] + red[3];
    float inv = 1.0f / sum;
#pragma unroll
    for (int i = 0; i < 4; i++) pr[i * 256 + t] = sc[i] * inv;
    __syncthreads();
    float acc = 0.f;
    const int d = lane, kb = wv * 256;
    for (int kk = 0; kk < 256; kk++) {
        int k = kb + kk;
        acc = fmaf(pr[k], vh[((size_t)b * Ln + k) * HDn + h * 64 + d], acc);
    }
    part[wv][d] = acc;
    __syncthreads();
    if (t < 64) s_out[(size_t)b * 1024 + h * 64 + t] = part[0][t] + part[1][t] + part[2][t] + part[3][t];
}

// ---------------- su = [s_out, state] @ Wfs^T + bfs --------------------------
__global__ __launch_bounds__(256) void su_gemm_kernel(
    const float* __restrict__ s_out, const float* __restrict__ state,
    const float* __restrict__ Wfs, const float* __restrict__ bfs,
    float* __restrict__ su_pre)
{
    __shared__ float x[1536];
    const int b = blockIdx.x, t = threadIdx.x, lane = t & 63, wv = t >> 6;
    for (int i = t; i < 1024; i += 256) x[i] = s_out[(size_t)b * 1024 + i];
    for (int i = t; i < 512; i += 256) x[1024 + i] = state[(size_t)b * 512 + i];
    __syncthreads();
    for (int o = 0; o < 128; o++) {
        int n = wv * 128 + o;
        float s = 0.f;
        for (int j = lane; j < 1536; j += 64) s = fmaf(x[j], Wfs[(size_t)n * 1536 + j], s);
        for (int off = 32; off; off >>= 1) s += __shfl_xor(s, off);
        if (lane == 0) su_pre[(size_t)b * 512 + n] = s + bfs[n];
    }
}

// ---------------- su LayerNorm over 512 -> d_out -----------------------------
__global__ __launch_bounds__(256) void su_ln_kernel(
    const float* __restrict__ pre, const float* __restrict__ g, const float* __restrict__ bb,
    float* __restrict__ out)
{
    __shared__ float sm[4];
    const int b = blockIdx.x, t = threadIdx.x, lane = t & 63, wv = t >> 6;
    float a = pre[(size_t)b * 512 + t];
    float c = pre[(size_t)b * 512 + 256 + t];
    float s = a + c;
    for (int o = 32; o; o >>= 1) s += __shfl_xor(s, o);
    if (lane == 0) sm[wv] = s;
    __syncthreads();
    float mean = (sm[0] + sm[1] + sm[2] + sm[3]) * (1.0f / 512.0f);
    __syncthreads();
    float da = a - mean, dc = c - mean;
    float q = da * da + dc * dc;
    for (int o = 32; o; o >>= 1) q += __shfl_xor(q, o);
    if (lane == 0) sm[wv] = q;
    __syncthreads();
    float var = (sm[0] + sm[1] + sm[2] + sm[3]) * (1.0f / 512.0f);
    float inv = 1.0f / sqrtf(var + 1e-5f);
    out[(size_t)b * 512 + t] = da * inv * g[t] + bb[t];
    out[(size_t)b * 512 + 256 + t] = dc * inv * g[256 + t] + bb[256 + t];
}

extern "C" void kernel_launch(void* const* d_in, const int* in_sizes, int n_in,
                              void* d_out, int out_size, void* d_ws, size_t ws_size,
                              hipStream_t stream)
{
    const float* q     = (const float*)d_in[0];
    const float* k     = (const float*)d_in[1];
    const float* v     = (const float*)d_in[2];
    const float* state = (const float*)d_in[3];
    const void*  mask  = d_in[4];
    const float* Wq  = (const float*)d_in[5];  const float* bq  = (const float*)d_in[6];
    const float* Wk  = (const float*)d_in[7];  const float* bk  = (const float*)d_in[8];
    const float* Wv  = (const float*)d_in[9];  const float* bv  = (const float*)d_in[10];
    const float* Wsq = (const float*)d_in[11]; const float* bsq = (const float*)d_in[12];
    const float* Wfc = (const float*)d_in[13]; const float* bfc = (const float*)d_in[14];
    const float* Wfs = (const float*)d_in[15]; const float* bfs = (const float*)d_in[16];
    const float* lng = (const float*)d_in[17]; const float* lnb = (const float*)d_in[18];
    const float* slg = (const float*)d_in[19]; const float* slb = (const float*)d_in[20];

    if (ws_size < WS_FLOATS * sizeof(float)) return;  // would corrupt; fail loudly via poisoned output

    float* ws  = (float*)d_ws;
    float* out = (float*)d_out;
    float* qh = ws + OFF_QH;
    float* kh = ws + OFF_KH;
    float* vh = ws + OFF_VH;
    float* pv = ws + OFF_PV;
    int* flag = (int*)(ws + OFF_FLAG);
    float* att = out + OUT_ATT;

    detect_mask_kernel<<<1, 256, 0, stream>>>((const unsigned int*)mask, flag);
    state_proj_kernel<<<dim3(5, 8, 16), 256, 0, stream>>>(state, Wq, bq, Wk, bk, Wv, bv, Wsq, bsq, Wfc, bfc, ws);

    dim3 gg(8, 64);
    gemm_nt_kernel<<<gg, 256, 0, stream>>>(q, Wq, ws + OFF_SPQ, nullptr, qh, 8192, 1024, 1024, KCn);
    gemm_nt_kernel<<<gg, 256, 0, stream>>>(k, Wk, ws + OFF_SPK, nullptr, kh, 8192, 1024, 1024, KCn);
    gemm_nt_kernel<<<gg, 256, 0, stream>>>(v, Wv, ws + OFF_SPV, nullptr, vh, 8192, 1024, 1024, KCn);

    score_gemm_kernel<<<dim3(8, 8, 128), 256, 0, stream>>>(qh, kh, mask, flag, att);
    softmax_kernel<<<dim3(131072), 256, 0, stream>>>(att);
    pv_gemm_kernel<<<dim3(1, 8, 128), 256, 0, stream>>>(att, vh, pv);

    // output projection + residual -> preLN (reuses qh region), then LN
    gemm_nt_kernel<<<gg, 256, 0, stream>>>(pv, Wfc, ws + OFF_FCS, q, ws + OFF_QH, 8192, 1024, 1024, KCn);
    ln_kernel<<<dim3(8192), 256, 0, stream>>>(ws + OFF_QH, lng, lnb, out);

    // state-query path
    state_attn_kernel<<<dim3(16, 8), 256, 0, stream>>>(kh, vh, ws + OFF_SQ, ws + OFF_SOUT);
    su_gemm_kernel<<<dim3(8), 256, 0, stream>>>(ws + OFF_SOUT, state, Wfs, bfs, ws + OFF_SUP);
    su_ln_kernel<<<dim3(8), 256, 0, stream>>>(ws + OFF_SUP, slg, slb, out + OUT_SU);
}